// Round 11
// baseline (145.545 us; speedup 1.0000x reference)
//
#include <hip/hip_runtime.h>

// Per-sample depthwise 7x7 cross-correlation, NHWC, SAME padding.
// inputs:  [B,H,W,C] fp32, kernels: [B,7,7,C] fp32, out: [B,H,W,C] fp32.
// out[b,y,x,c] = sum_{i,j} in[b, y+i-3, x+j-3, c] * ker[b,i,j,c]  (zero pad)
//
// R11: input rows staged through a double-buffered LDS ring (T14 split:
// issue global loads to regs EARLY, ds_write them LATE, __syncthreads per
// pass). Taps become low-latency LDS reads -> the per-pass global-latency
// stall (R10's limiter, VALUBusy 45% with no pipe saturated) disappears.
// Weights stay packed-fp16 in LDS (7 b128/pass). Staging regs = 8 -> total
// ~55 VGPRs, inside the 64-reg tier (8 waves/SIMD). No occupancy attributes,
// no multi-pass unrolling (R2/R6/R9 lessons).

#define BB 32
#define HH 128
#define WW 128
#define CC 128
#define KH 7
#define KW 7

#define XPT 4                        // x outputs per thread
#define NTAP (XPT + KW - 1)          // 10 tap columns per thread
#define XG 8                         // x-groups per block (1024 threads / 128 c)
#define SLABW (XG * XPT)             // 32 output columns per block
#define SLABC 40                     // staged cols: 32 + 6 halo + 2 pad
#define NXS (WW / SLABW)             // 4 x-slabs
#define YSPLIT 4
#define YROWS (HH / YSPLIT)          // 32 output rows per block
#define GRID (BB * NXS * YSPLIT)     // 512 blocks = 2 per CU
#define WSLOTS 28                    // per-c packed-weight uints (7 rows x 4 pairs)
#define NPASS (YROWS + KH - 1)       // 38 single-row passes
#define ROWELEM (SLABC * CC)         // 5120 floats = 20480 B per row buffer

typedef _Float16 half2_t __attribute__((ext_vector_type(2)));

static __device__ __forceinline__ half2_t pk(float a, float b) {
#if __has_builtin(__builtin_amdgcn_cvt_pkrtz)
    return __builtin_bit_cast(half2_t, __builtin_amdgcn_cvt_pkrtz(a, b));
#else
    half2_t r; r.x = (_Float16)a; r.y = (_Float16)b; return r;
#endif
}

static __device__ __forceinline__ float dot2f(unsigned w, half2_t t, float c) {
#if __has_builtin(__builtin_amdgcn_fdot2)
    return __builtin_amdgcn_fdot2(__builtin_bit_cast(half2_t, w), t, c, false);
#else
    half2_t wv = __builtin_bit_cast(half2_t, w);
    return fmaf((float)wv.x, (float)t.x, fmaf((float)wv.y, (float)t.y, c));
#endif
}

__global__ __launch_bounds__(1024) void crossconv_kernel(
    const float* __restrict__ in,
    const float* __restrict__ ker,
    float* __restrict__ out)
{
    __shared__ unsigned lds_w[CC * WSLOTS];   // 14336 B
    __shared__ float    lds_in[2][ROWELEM];   // 2 x 20480 B   (total 55296 B)

    const int tid = threadIdx.x;
    const int c  = tid & (CC - 1);   // lanes contiguous in c -> coalesced
    const int xg = __builtin_amdgcn_readfirstlane(tid >> 7);   // 0..7, wave-uniform

    // Bijective XCD swizzle (GRID=512, 64 blocks/XCD = 4 whole samples).
    const int bid = blockIdx.x;
    const int swz = (bid & 7) * (GRID / 8) + (bid >> 3);
    const int b  = swz >> 4;         // 16 blocks per sample
    const int xs = (swz >> 2) & 3;
    const int yh = swz & 3;
    const int xstart = xs * SLABW;
    const int x0 = xstart + xg * XPT;     // wave-uniform (scalar)
    const int y0 = yh * YROWS;

    // ---- Stage packed weights into LDS: slot s -> row i=s>>2, pair q=s&3 ----
    {
        const float* kb = ker + ((size_t)b * KH * KW) * CC + c;
        for (int s = xg; s < WSLOTS; s += XG) {
            const int i = s >> 2, q = s & 3;
            half2_t pr;
            if (q < 3) {
                const int f0 = i * KW + 2 * q;
                pr = pk(kb[f0 * CC], kb[(f0 + 1) * CC]);
            } else {
                pr = pk(kb[(i * KW + 6) * CC], 0.0f);
            }
            lds_w[c * WSLOTS + s] = __builtin_bit_cast(unsigned, pr);
        }
    }

    const char*  inb  = (const char*)in + (size_t)b * HH * WW * CC * 4;
    float*       ob   = out + ((size_t)b * HH * WW) * CC;
    const unsigned* wlds = &lds_w[c * WSLOTS];

    // ---- Per-thread staging geometry (float4 granularity) ----
    // Row buffer = 1280 float4; thread t takes e4 = t, threads < 256 also
    // e4 = t + 1024. e4 -> slab col e4>>5, floats (e4&31)*4..+3.
    const int  coff  = (tid & 31) * 16;                       // bytes within col
    const int  gc0   = min(max(xstart - 3 + (tid >> 5), 0), WW - 1);
    const bool extra = (tid < 256);
    const int  gc1   = min(max(xstart - 3 + 32 + (tid >> 5), 0), WW - 1);
    const int  goff0 = gc0 * (CC * 4) + coff;                 // bytes within row
    const int  goff1 = gc1 * (CC * 4) + coff;
    const int  loff0 = tid * 16;                              // LDS bytes
    const int  loff1 = (tid + 1024) * 16;

    const bool interior = (x0 >= 3) && (x0 + XPT + 2 < WW);
    const int  yi0v = y0 - 3;

    // ---- Prologue: stage first row (if valid) into buf[0] ----
    if (yi0v >= 0 && yi0v < HH) {
        const char* rowb = inb + (size_t)yi0v * (WW * CC * 4);
        float4 s0 = *(const float4*)(rowb + goff0);
        *(float4*)((char*)lds_in[0] + loff0) = s0;
        if (extra) {
            float4 s1 = *(const float4*)(rowb + goff1);
            *(float4*)((char*)lds_in[0] + loff1) = s1;
        }
    }
    __syncthreads();

    // Sliding ring: acc[s][xo] partial for output row y = yi-3+s.
    float acc[KH][XPT];
    #pragma unroll
    for (int s = 0; s < KH; ++s)
        #pragma unroll
        for (int xo = 0; xo < XPT; ++xo) acc[s][xo] = 0.0f;

    #pragma unroll 1
    for (int p = 0; p < NPASS; ++p) {
        const int yi = yi0v + p;

        // ---- A: issue staging loads for row yi+1 (consumed next pass) ----
        float4 g0, g1;
        const int rnext = yi + 1;
        const bool dostage = (rnext >= 0) && (rnext < HH) && (p + 1 < NPASS);
        if (dostage) {
            const char* rowb = inb + (size_t)rnext * (WW * CC * 4);
            g0 = *(const float4*)(rowb + goff0);
            if (extra) g1 = *(const float4*)(rowb + goff1);
        }

        // ---- B: compute input row yi from buf[p&1] ----
        if (yi >= 0 && yi < HH) {           // block-uniform branch
            const float* buf = lds_in[p & 1];
            float t[NTAP];
            if (interior) {
                #pragma unroll
                for (int j = 0; j < NTAP; ++j)
                    t[j] = buf[(xg * XPT + j) * CC + c];
            } else {
                #pragma unroll
                for (int j = 0; j < NTAP; ++j) {
                    const int xx = x0 - 3 + j;
                    t[j] = (xx >= 0 && xx < WW) ? buf[(xg * XPT + j) * CC + c]
                                                : 0.0f;
                }
            }

            // Pack taps: e[k]=(t[2k],t[2k+1]); o[k]=(t[2k+1],t[2k+2]); o[4]=(t9,0).
            half2_t e[5], o[5];
            #pragma unroll
            for (int k = 0; k < 5; ++k) e[k] = pk(t[2 * k], t[2 * k + 1]);
            #pragma unroll
            for (int k = 0; k < 4; ++k) o[k] = pk(t[2 * k + 1], t[2 * k + 2]);
            o[4] = pk(t[9], 0.0f);

            // Blocks weight-read hoisting (would spill) AND pins the staging
            // loads above the dot pass (they may not sink across this fence).
            asm volatile("" ::: "memory");

            #pragma unroll
            for (int i = 0; i < KH; ++i) {
                const uint4 wq = *(const uint4*)(wlds + i * 4);  // kernel row i
                const int s = 6 - i;
                #pragma unroll
                for (int xo = 0; xo < XPT; ++xo) {
                    float a = acc[s][xo];
                    if ((xo & 1) == 0) {
                        const int k0 = xo >> 1;
                        a = dot2f(wq.x, e[k0],     a);
                        a = dot2f(wq.y, e[k0 + 1], a);
                        a = dot2f(wq.z, e[k0 + 2], a);
                        a = dot2f(wq.w, e[k0 + 3], a);
                    } else {
                        const int k0 = (xo - 1) >> 1;
                        a = dot2f(wq.x, o[k0],     a);
                        a = dot2f(wq.y, o[k0 + 1], a);
                        a = dot2f(wq.z, o[k0 + 2], a);
                        a = dot2f(wq.w, o[k0 + 3], a);
                    }
                    acc[s][xo] = a;
                }
            }
        }

        // ---- C: output row y = yi-3 completes in slot 0 ----
        const int y = yi - 3;
        if (y >= y0) {                       // upper bound guaranteed by loop end
            float* orow = ob + ((size_t)y * WW + x0) * CC + c;
            #pragma unroll
            for (int xo = 0; xo < XPT; ++xo)
                orow[xo * CC] = acc[0][xo];
        }
        // Shift ring, open fresh top slot.
        #pragma unroll
        for (int s = 0; s < KH - 1; ++s)
            #pragma unroll
            for (int xo = 0; xo < XPT; ++xo) acc[s][xo] = acc[s + 1][xo];
        #pragma unroll
        for (int xo = 0; xo < XPT; ++xo) acc[KH - 1][xo] = 0.0f;

        // ---- D: write staged row into the other buffer (auto vmcnt wait) ----
        if (dostage) {
            char* dst = (char*)lds_in[(p + 1) & 1];
            *(float4*)(dst + loff0) = g0;
            if (extra) *(float4*)(dst + loff1) = g1;
        }
        __syncthreads();
    }
}

extern "C" void kernel_launch(void* const* d_in, const int* in_sizes, int n_in,
                              void* d_out, int out_size, void* d_ws, size_t ws_size,
                              hipStream_t stream) {
    const float* in  = (const float*)d_in[0];
    const float* ker = (const float*)d_in[1];
    float*       out = (float*)d_out;

    crossconv_kernel<<<GRID, 1024, 0, stream>>>(in, ker, out);
}